// Round 4
// baseline (2795.700 us; speedup 1.0000x reference)
//
#include <hip/hip_runtime.h>

// EnhancedRGCN on MI355X — split-f16 MFMA GEMMs (fp32-accurate via hi/lo
// decomposition, 3 MFMA terms), CSR-gather aggregations, fp32 elementwise.
//
// x = hi + lo/512, hi=f16(x), lo=f16((x-hi)*512). A@W = hiA@hiW +
// (hiA@loW + loA@hiW)/512; cross terms share one accumulator.
//
// Round 4:
//  - gemm_ps: A triple-buffered depth-2 DMA pipeline (vmcnt 6/4/0 | 5/3/0),
//    XOR key (row>>1)&3 -> 8 distinct bank starts (conflict-free ds_read).
//  - FF1: depth-2 register prefetch (2 named sets, unrolled x2).
//  - conv1/conv2 t->{card,merch} projections fused into one N=256 GEMM.
//  - post-FF (gather + 64->64->64->1) fused into one kernel, LDS-resident.

#define NT 300000
#define NC 100000
#define NM 20000
#define DIN 390
#define DD 128
#define DOUT 64
#define HPRE 256
#define HPOST 64

typedef _Float16 half8 __attribute__((ext_vector_type(8)));
typedef _Float16 half4v __attribute__((ext_vector_type(4)));
typedef float f32x16 __attribute__((ext_vector_type(16)));
typedef float f32x4 __attribute__((ext_vector_type(4)));

#define LO_SCALE 512.0f
#define LO_INV   (1.0f / 512.0f)

__device__ __forceinline__ void split2(float x, _Float16& h, _Float16& l) {
    _Float16 hh = (_Float16)x;
    h = hh;
    l = (_Float16)((x - (float)hh) * LO_SCALE);
}

__device__ __forceinline__ void gload16(const _Float16* g, _Float16* l) {
    __builtin_amdgcn_global_load_lds(
        (const __attribute__((address_space(1))) void*)g,
        (__attribute__((address_space(3))) void*)l, 16, 0, 0);
}

// ---------------------------------------------------------------------------
// gemm_ps: C = act((A@W) * rowscale + bias), A pre-split hi/lo planes
// [Mpad][Kpad] f16, W pre-split planes [N][Kpad] f16. BM=128, BN=64*TN.
// 512 threads (8 waves). A: 3 LDS buffers (depth-2 DMA); B: 2 buffers.
// Counted vmcnt keeps 2 A-tiles + 1 B-tile in flight across barriers.
// Swizzle: phys 16B-chunk = logical ^ ((row>>1)&3), linear DMA dest,
// inverse-swizzled global source (rule: both-sides-or-neither).
// ---------------------------------------------------------------------------
template<int TN>
__global__ __launch_bounds__(512, 4) void gemm_ps(
    const _Float16* __restrict__ Agh, const _Float16* __restrict__ Agl,
    const _Float16* __restrict__ Bgh, const _Float16* __restrict__ Bgl,
    const float* __restrict__ bias, const float* __restrict__ rowscale,
    _Float16* __restrict__ Ch, _Float16* __restrict__ Cl,
    float* __restrict__ C32,
    int M, int Kpad, int N, int relu)
{
    constexpr int BM = 128;
    constexpr int BN = 64 * TN;
    constexpr int BHALF = BN * 32;          // B hi-plane halves per buffer
    constexpr int BUFB  = 2 * BHALF;        // B buffer (hi+lo) halves
    constexpr int OFF_B = 24576;            // after 3 A buffers (3*8192)
    __shared__ __align__(16) _Float16 smem[OFF_B + 2 * BUFB];

    const int tid  = (int)threadIdx.x;
    const int lane = tid & 63;
    const int wave = tid >> 6;
    const int wm0  = (wave & 3) * 32;
    const int wn0  = (wave >> 2) * 32 * TN;

    const int nbn  = N / BN;
    const int bm   = ((int)blockIdx.x / nbn) * BM;
    const int bn   = ((int)blockIdx.x % nbn) * BN;

    // staging roles: 16B per thread per plane; source pre-swizzled
    const int srow = lane >> 2;                                  // 0..15
    const int xc8  = (((lane & 3) ^ ((srow >> 1) & 3)) << 3);    // k halves
    const size_t a_off = (size_t)(bm + wave * 16 + srow) * Kpad + xc8;
    size_t b_off;
    if constexpr (TN == 2) {
        b_off = (size_t)(bn + wave * 16 + srow) * Kpad + xc8;
    } else {
        b_off = (size_t)(bn + (wave & 3) * 16 + srow) * Kpad + xc8;
    }

    auto stageA = [&](int ab, int k0) {
        _Float16* base = &smem[ab * 8192];
        gload16(Agh + a_off + k0, base + wave * 512);
        gload16(Agl + a_off + k0, base + 4096 + wave * 512);
    };
    auto stageB = [&](int bb, int k0) {
        _Float16* base = &smem[OFF_B + bb * BUFB];
        if constexpr (TN == 2) {
            gload16(Bgh + b_off + k0, base + wave * 512);
            gload16(Bgl + b_off + k0, base + BHALF + wave * 512);
        } else {
            gload16((wave < 4 ? Bgh : Bgl) + b_off + k0,
                    base + (wave < 4 ? 0 : BHALF) + (wave & 3) * 512);
        }
    };

    f32x16 zz;
    #pragma unroll
    for (int i = 0; i < 16; ++i) zz[i] = 0.f;
    f32x16 acc_hh[TN], acc_x[TN];
    #pragma unroll
    for (int t2 = 0; t2 < TN; ++t2) { acc_hh[t2] = zz; acc_x[t2] = zz; }

    const int mlr = lane & 31;          // MFMA m/n index
    const int hi5 = lane >> 5;          // k sub-group
    const int xr  = (mlr >> 1) & 3;     // read-side swizzle key

    const int NS = Kpad >> 5;

    // prologue: issue order B(0), A(0), A(1)  (vmcnt math depends on it)
    stageB(0, 0);
    stageA(0, 0);
    if (NS > 1) stageA(1, 32);

    int ca = 0, cn = 2;   // current A buf; stage target = (t+2)%3

    for (int t = 0; t < NS; ++t) {
        if (t + 1 < NS) stageB((t + 1) & 1, (t + 1) << 5);
        if (t + 2 < NS) stageA(cn, (t + 2) << 5);

        if (t + 2 < NS) {
            asm volatile("s_waitcnt vmcnt(%0)" :: "n"(TN == 2 ? 6 : 5) : "memory");
        } else if (t + 1 < NS) {
            asm volatile("s_waitcnt vmcnt(%0)" :: "n"(TN == 2 ? 4 : 3) : "memory");
        } else {
            asm volatile("s_waitcnt vmcnt(0)" ::: "memory");
        }
        __builtin_amdgcn_s_barrier();
        __builtin_amdgcn_sched_barrier(0);

        const _Float16* sa = &smem[ca * 8192];
        const _Float16* sb = &smem[OFF_B + (t & 1) * BUFB];
        #pragma unroll
        for (int ks = 0; ks < 2; ++ks) {
            const int xo = (((ks * 2 + hi5) ^ xr) << 3);
            const half8 fah = *(const half8*)&sa[(wm0 + mlr) * 32 + xo];
            const half8 fal = *(const half8*)&sa[4096 + (wm0 + mlr) * 32 + xo];
            half8 fbh[TN], fbl[TN];
            #pragma unroll
            for (int t2 = 0; t2 < TN; ++t2) {
                const int nn = wn0 + t2 * 32 + mlr;
                fbh[t2] = *(const half8*)&sb[nn * 32 + xo];
                fbl[t2] = *(const half8*)&sb[BHALF + nn * 32 + xo];
            }
            #pragma unroll
            for (int t2 = 0; t2 < TN; ++t2) {
                acc_hh[t2] = __builtin_amdgcn_mfma_f32_32x32x16_f16(
                    fah, fbh[t2], acc_hh[t2], 0, 0, 0);
                acc_x[t2] = __builtin_amdgcn_mfma_f32_32x32x16_f16(
                    fah, fbl[t2], acc_x[t2], 0, 0, 0);
                acc_x[t2] = __builtin_amdgcn_mfma_f32_32x32x16_f16(
                    fal, fbh[t2], acc_x[t2], 0, 0, 0);
            }
        }
        __builtin_amdgcn_sched_barrier(0);
        __builtin_amdgcn_s_barrier();

        ca = (ca == 2) ? 0 : ca + 1;
        cn = (cn == 2) ? 0 : cn + 1;
    }

    // ---- epilogue ----
    const int r0 = 4 * hi5;
    #pragma unroll
    for (int t2 = 0; t2 < TN; ++t2) {
        const int gcol = bn + wn0 + t2 * 32 + mlr;
        const float bc = (bias != nullptr) ? bias[gcol] : 0.f;
        #pragma unroll
        for (int r = 0; r < 16; ++r) {
            const int grow = bm + wm0 + (r & 3) + r0 + 8 * (r >> 2);
            if (grow < M) {
                float v = acc_hh[t2][r] + acc_x[t2][r] * LO_INV;
                if (rowscale != nullptr) v *= rowscale[grow];
                v += bc;
                if (relu) v = fmaxf(v, 0.f);
                if (C32 != nullptr) {
                    C32[(size_t)grow * N + gcol] = v;
                } else {
                    _Float16 hh, ll;
                    split2(v, hh, ll);
                    Ch[(size_t)grow * N + gcol] = hh;
                    Cl[(size_t)grow * N + gcol] = ll;
                }
            }
        }
    }
}

// ---------------------------------------------------------------------------
// Register-split GEMM for FF1 (A = raw fp32 input). BM=64, BN=128,
// 256 threads. Depth-2 register prefetch (2 named sets, unrolled x2).
// ---------------------------------------------------------------------------
template<int TM, int TN, int WGM, int WGN>
__global__ __launch_bounds__(256, 3) void gemm_mfma(
    const float* __restrict__ A, const _Float16* __restrict__ Wh,
    const _Float16* __restrict__ Wl, const float* __restrict__ bias,
    const float* __restrict__ rowscale,
    float* __restrict__ C32, _Float16* __restrict__ Ch, _Float16* __restrict__ Cl,
    int M, int K, int N, int Kpad, int relu)
{
    constexpr int BM = 32 * TM * WGM;
    constexpr int BN = 32 * TN * WGN;
    constexpr int RS = 40;
    __shared__ __align__(16) _Float16 Ah[BM * RS];
    __shared__ __align__(16) _Float16 Al[BM * RS];
    __shared__ __align__(16) _Float16 Bh[BN * RS];
    __shared__ __align__(16) _Float16 Bl[BN * RS];

    const int tid  = (int)threadIdx.x;
    const int lane = tid & 63;
    const int wave = tid >> 6;
    const int wm0 = (wave % WGM) * 32 * TM;
    const int wn0 = (wave / WGM) * 32 * TN;

    const int nbn = N / BN;
    const int tile = (int)blockIdx.x;
    const int bm = (tile / nbn) * BM;
    const int bn = (tile % nbn) * BN;

    f32x16 zz;
    #pragma unroll
    for (int i = 0; i < 16; ++i) zz[i] = 0.f;
    f32x16 acc_hh[TM][TN], acc_x[TM][TN];
    #pragma unroll
    for (int tm = 0; tm < TM; ++tm)
        #pragma unroll
        for (int tn = 0; tn < TN; ++tn) { acc_hh[tm][tn] = zz; acc_x[tm][tn] = zz; }

    constexpr int TPR  = 256 / BM;
    constexpr int KPT  = 32 / TPR;
    constexpr int FQ   = KPT / 4;
    const int sar = tid / TPR;
    const int sak = (tid % TPR) * KPT;
    const int agrow = bm + sar;
    const float* Aptr = A + (size_t)agrow * K;

    constexpr int TPRB = 256 / BN;
    constexpr int KPTB = 32 / TPRB;
    constexpr int NB   = KPTB / 8;
    const int sbr = tid / TPRB;
    const int sbk = (tid % TPRB) * KPTB;
    const _Float16* Bhp = Wh + (size_t)(bn + sbr) * Kpad + sbk;
    const _Float16* Blp = Wl + (size_t)(bn + sbr) * Kpad + sbk;

    const int ml  = lane & 31;
    const int klo = (lane >> 5) * 8;

    f32x4 areg0[FQ], areg1[FQ];
    half8 bh0[NB], bl0[NB], bh1[NB], bl1[NB];

    auto loadA = [&](f32x4 (&ar)[FQ], int k0) {
        #pragma unroll
        for (int q = 0; q < FQ; ++q) {
            const int kb = k0 + sak + q * 4;
            f32x4 f = {0.f, 0.f, 0.f, 0.f};
            if (agrow < M) {
                if (kb + 3 < K) {
                    f = *(const f32x4*)(Aptr + kb);
                } else {
                    if (kb + 0 < K) f[0] = Aptr[kb + 0];
                    if (kb + 1 < K) f[1] = Aptr[kb + 1];
                    if (kb + 2 < K) f[2] = Aptr[kb + 2];
                    if (kb + 3 < K) f[3] = Aptr[kb + 3];
                }
            }
            ar[q] = f;
        }
    };
    auto loadB = [&](half8 (&bh)[NB], half8 (&bl)[NB], int k0) {
        #pragma unroll
        for (int j = 0; j < NB; ++j) {
            bh[j] = *(const half8*)(Bhp + k0 + j * 8);
            bl[j] = *(const half8*)(Blp + k0 + j * 8);
        }
    };

    loadA(areg0, 0);
    loadB(bh0, bl0, 0);
    if (32 < K) { loadA(areg1, 32); loadB(bh1, bl1, 32); }

    auto step = [&](f32x4 (&ar)[FQ], half8 (&bh)[NB], half8 (&bl)[NB], int k0) {
        #pragma unroll
        for (int c = 0; c < FQ / 2; ++c) {
            half8 h, l;
            #pragma unroll
            for (int q = 0; q < 2; ++q) {
                #pragma unroll
                for (int j = 0; j < 4; ++j) {
                    _Float16 th, tl;
                    split2(ar[2 * c + q][j], th, tl);
                    h[q * 4 + j] = th;
                    l[q * 4 + j] = tl;
                }
            }
            *(half8*)&Ah[sar * RS + sak + c * 8] = h;
            *(half8*)&Al[sar * RS + sak + c * 8] = l;
        }
        #pragma unroll
        for (int j = 0; j < NB; ++j) {
            *(half8*)&Bh[sbr * RS + sbk + j * 8] = bh[j];
            *(half8*)&Bl[sbr * RS + sbk + j * 8] = bl[j];
        }
        __syncthreads();

        // prefetch tile k0+64 into this (now-consumed) set: 2-deep window
        if (k0 + 64 < K) { loadA(ar, k0 + 64); loadB(bh, bl, k0 + 64); }

        #pragma unroll
        for (int ks = 0; ks < 2; ++ks) {
            const int kk = ks * 16 + klo;
            half8 fah[TM], fal[TM], fbh[TN], fbl[TN];
            #pragma unroll
            for (int t = 0; t < TM; ++t) {
                const int m = wm0 + t * 32 + ml;
                fah[t] = *(const half8*)&Ah[m * RS + kk];
                fal[t] = *(const half8*)&Al[m * RS + kk];
            }
            #pragma unroll
            for (int t = 0; t < TN; ++t) {
                const int n = wn0 + t * 32 + ml;
                fbh[t] = *(const half8*)&Bh[n * RS + kk];
                fbl[t] = *(const half8*)&Bl[n * RS + kk];
            }
            #pragma unroll
            for (int tm = 0; tm < TM; ++tm)
                #pragma unroll
                for (int tn = 0; tn < TN; ++tn) {
                    acc_hh[tm][tn] = __builtin_amdgcn_mfma_f32_32x32x16_f16(
                        fah[tm], fbh[tn], acc_hh[tm][tn], 0, 0, 0);
                    acc_x[tm][tn] = __builtin_amdgcn_mfma_f32_32x32x16_f16(
                        fah[tm], fbl[tn], acc_x[tm][tn], 0, 0, 0);
                    acc_x[tm][tn] = __builtin_amdgcn_mfma_f32_32x32x16_f16(
                        fal[tm], fbh[tn], acc_x[tm][tn], 0, 0, 0);
                }
        }
        __syncthreads();
    };

    for (int k0 = 0; k0 < K; k0 += 64) {
        step(areg0, bh0, bl0, k0);
        if (k0 + 32 < K) step(areg1, bh1, bl1, k0 + 32);
    }

    const int r0 = 4 * (lane >> 5);
    #pragma unroll
    for (int tm = 0; tm < TM; ++tm) {
        #pragma unroll
        for (int tn = 0; tn < TN; ++tn) {
            const int gcol = bn + wn0 + tn * 32 + ml;
            const float bc = (bias != nullptr) ? bias[gcol] : 0.f;
            #pragma unroll
            for (int r = 0; r < 16; ++r) {
                const int grow = bm + wm0 + tm * 32 + (r & 3) + r0 + 8 * (r >> 2);
                if (grow < M) {
                    float v = acc_hh[tm][tn][r] + acc_x[tm][tn][r] * LO_INV;
                    if (rowscale != nullptr) v *= rowscale[grow];
                    v += bc;
                    if (relu) v = fmaxf(v, 0.f);
                    if (C32 != nullptr) {
                        C32[(size_t)grow * N + gcol] = v;
                    } else {
                        _Float16 hh, ll;
                        split2(v, hh, ll);
                        Ch[(size_t)grow * N + gcol] = hh;
                        Cl[(size_t)grow * N + gcol] = ll;
                    }
                }
            }
        }
    }
}

// ---------------------------------------------------------------------------
// Fused post-FF: per 128-row block: gather h3 = hc[card]+hm[merch]+bt0+bt1,
// then h=relu(h3@Wi+bi) -> h=relu(h@Wh+bh) -> out=h@Wo+bo. All intermediates
// in LDS (planes, padded stride 72 -> conflict-free ds_read_b128).
// ---------------------------------------------------------------------------
__global__ __launch_bounds__(512, 2) void post_ff(
    const float* __restrict__ hc, const float* __restrict__ hm,
    const int* __restrict__ card, const int* __restrict__ merch,
    const float* __restrict__ bt0, const float* __restrict__ bt1,
    const _Float16* __restrict__ wih, const _Float16* __restrict__ wil,
    const float* __restrict__ bi,
    const _Float16* __restrict__ whh, const _Float16* __restrict__ whl,
    const float* __restrict__ bh,
    const float* __restrict__ wo, const float* __restrict__ bo,
    float* __restrict__ out, int n)
{
    constexpr int SR = 72;               // plane row stride (halves)
    constexpr int OFF_AH = 0;            // 128*72 = 9216
    constexpr int OFF_AL = 9216;
    constexpr int OFF_HH = 18432;
    constexpr int OFF_HL = 27648;
    constexpr int OFF_W1H = 36864;       // 64*72 = 4608
    constexpr int OFF_W1L = 41472;
    constexpr int OFF_W2H = 46080;
    constexpr int OFF_W2L = 50688;
    __shared__ __align__(16) _Float16 S[55296];   // 108 KB
    float* sh2 = (float*)&S[OFF_AH];     // overlay A region (dead after L1)

    const int tid  = (int)threadIdx.x;
    const int lane = tid & 63;
    const int wave = tid >> 6;
    const int bm   = (int)blockIdx.x * 128;

    // ---- stage W planes ([64][64] global -> [64][SR] LDS) ----
    {
        const int wn = (tid & 255) >> 2;
        const int c0 = (tid & 3) * 16;
        const _Float16* gh = (tid < 256) ? wih : whh;
        const _Float16* gl = (tid < 256) ? wil : whl;
        const int oh = (tid < 256) ? OFF_W1H : OFF_W2H;
        const int ol = (tid < 256) ? OFF_W1L : OFF_W2L;
        *(half8*)&S[oh + wn * SR + c0]     = *(const half8*)(gh + wn * 64 + c0);
        *(half8*)&S[oh + wn * SR + c0 + 8] = *(const half8*)(gh + wn * 64 + c0 + 8);
        *(half8*)&S[ol + wn * SR + c0]     = *(const half8*)(gl + wn * 64 + c0);
        *(half8*)&S[ol + wn * SR + c0 + 8] = *(const half8*)(gl + wn * 64 + c0 + 8);
    }
    // ---- gather + split A (h3) ----
    {
        const int r  = tid >> 2;
        const int c0 = (tid & 3) << 4;
        const int t  = bm + r;
        const bool ok = (t < n);
        const int ci = ok ? card[t] : 0;
        const int mi = ok ? merch[t] : 0;
        #pragma unroll
        for (int q = 0; q < 4; ++q) {
            const int c = c0 + q * 4;
            float4 a = make_float4(0.f, 0.f, 0.f, 0.f);
            if (ok) {
                float4 va = *(const float4*)(hc + (size_t)ci * 64 + c);
                float4 vb = *(const float4*)(hm + (size_t)mi * 64 + c);
                float4 b0 = *(const float4*)(bt0 + c);
                float4 b1 = *(const float4*)(bt1 + c);
                a.x = va.x + vb.x + b0.x + b1.x;
                a.y = va.y + vb.y + b0.y + b1.y;
                a.z = va.z + vb.z + b0.z + b1.z;
                a.w = va.w + vb.w + b0.w + b1.w;
            }
            half4v h, l;
            _Float16 th, tl;
            split2(a.x, th, tl); h[0] = th; l[0] = tl;
            split2(a.y, th, tl); h[1] = th; l[1] = tl;
            split2(a.z, th, tl); h[2] = th; l[2] = tl;
            split2(a.w, th, tl); h[3] = th; l[3] = tl;
            *(half4v*)&S[OFF_AH + r * SR + c] = h;
            *(half4v*)&S[OFF_AL + r * SR + c] = l;
        }
    }
    __syncthreads();

    const int mlr = lane & 31;
    const int hi5 = lane >> 5;
    const int wm = (wave & 3) * 32;
    const int wn = (wave >> 2) * 32;
    const int r0 = 4 * hi5;

    f32x16 zz;
    #pragma unroll
    for (int i = 0; i < 16; ++i) zz[i] = 0.f;

    // ---- layer 1: h = relu(A@Wi + bi) -> planes in sH ----
    {
        f32x16 acc = zz, accx = zz;
        #pragma unroll
        for (int ks = 0; ks < 4; ++ks) {
            const int kk = ks * 16 + hi5 * 8;
            const half8 fah = *(const half8*)&S[OFF_AH + (wm + mlr) * SR + kk];
            const half8 fal = *(const half8*)&S[OFF_AL + (wm + mlr) * SR + kk];
            const half8 fbh = *(const half8*)&S[OFF_W1H + (wn + mlr) * SR + kk];
            const half8 fbl = *(const half8*)&S[OFF_W1L + (wn + mlr) * SR + kk];
            acc  = __builtin_amdgcn_mfma_f32_32x32x16_f16(fah, fbh, acc, 0, 0, 0);
            accx = __builtin_amdgcn_mfma_f32_32x32x16_f16(fah, fbl, accx, 0, 0, 0);
            accx = __builtin_amdgcn_mfma_f32_32x32x16_f16(fal, fbh, accx, 0, 0, 0);
        }
        const float bc = bi[wn + mlr];
        __syncthreads();   // A reads done before sH writes alias nothing; keep order safe
        #pragma unroll
        for (int r = 0; r < 16; ++r) {
            const int row = wm + (r & 3) + r0 + 8 * (r >> 2);
            float v = acc[r] + accx[r] * LO_INV + bc;
            v = fmaxf(v, 0.f);
            _Float16 hh, ll;
            split2(v, hh, ll);
            S[OFF_HH + row * SR + wn + mlr] = hh;
            S[OFF_HL + row * SR + wn + mlr] = ll;
        }
    }
    __syncthreads();

    // ---- layer 2: h2 = relu(h@Wh + bh) -> fp32 in sh2 (overlays A) ----
    {
        f32x16 acc = zz, accx = zz;
        #pragma unroll
        for (int ks = 0; ks < 4; ++ks) {
            const int kk = ks * 16 + hi5 * 8;
            const half8 fah = *(const half8*)&S[OFF_HH + (wm + mlr) * SR + kk];
            const half8 fal = *(const half8*)&S[OFF_HL + (wm + mlr) * SR + kk];
            const half8 fbh = *(const half8*)&S[OFF_W2H + (wn + mlr) * SR + kk];
            const half8 fbl = *(const half8*)&S[OFF_W2L + (wn + mlr) * SR + kk];
            acc  = __builtin_amdgcn_mfma_f32_32x32x16_f16(fah, fbh, acc, 0, 0, 0);
            accx = __builtin_amdgcn_mfma_f32_32x32x16_f16(fah, fbl, accx, 0, 0, 0);
            accx = __builtin_amdgcn_mfma_f32_32x32x16_f16(fal, fbh, accx, 0, 0, 0);
        }
        const float bc = bh[wn + mlr];
        __syncthreads();   // ensure all layer-1/A reads done before sh2 overlay write
        #pragma unroll
        for (int r = 0; r < 16; ++r) {
            const int row = wm + (r & 3) + r0 + 8 * (r >> 2);
            float v = acc[r] + accx[r] * LO_INV + bc;
            sh2[row * 68 + wn + mlr] = fmaxf(v, 0.f);
        }
    }
    __syncthreads();

    // ---- output: out[t] = h2 . wo + bo ----
    if (tid < 128) {
        const int t = bm + tid;
        if (t < n) {
            float s = bo[0];
            #pragma unroll 8
            for (int c = 0; c < 64; ++c) s += sh2[tid * 68 + c] * wo[c];
            out[t] = s;
        }
    }
}

// W[e][k][n] fp32 -> hiT/loT [e][n][Kpad] f16 planes (zero-padded K -> Kpad)
__global__ void split_w(const float* __restrict__ W, _Float16* __restrict__ hiT,
                        _Float16* __restrict__ loT, int K, int N, int Kpad, int nmat)
{
    int idx = blockIdx.x * blockDim.x + threadIdx.x;
    int total = nmat * N * Kpad;
    if (idx >= total) return;
    int e = idx / (N * Kpad);
    int rem = idx - e * (N * Kpad);
    int n = rem / Kpad;
    int k = rem - n * Kpad;
    float v = (k < K) ? W[((size_t)e * K + k) * N + n] : 0.f;
    _Float16 h = (_Float16)v;
    hiT[idx] = h;
    loT[idx] = (_Float16)((v - (float)h) * LO_SCALE);
}

// X[M][K] fp32 row-major -> hi/lo planes [Mpad][K], pad rows zero
__global__ void split_a(const float* __restrict__ X, _Float16* __restrict__ xh,
                        _Float16* __restrict__ xl, int M, int Mpad, int K)
{
    int idx = blockIdx.x * blockDim.x + threadIdx.x;
    int per = K >> 3;
    int total = Mpad * per;
    if (idx >= total) return;
    int row = idx / per;
    int k = (idx - row * per) << 3;
    half8 h, l;
    if (row < M) {
        #pragma unroll
        for (int j = 0; j < 8; ++j) {
            _Float16 th, tl;
            split2(X[(size_t)row * K + k + j], th, tl);
            h[j] = th; l[j] = tl;
        }
    } else {
        #pragma unroll
        for (int j = 0; j < 8; ++j) { h[j] = (_Float16)0.f; l[j] = (_Float16)0.f; }
    }
    *(half8*)&xh[(size_t)row * K + k] = h;
    *(half8*)&xl[(size_t)row * K + k] = l;
}

// ---------------------------------------------------------------------------
// Graph helper kernels
// ---------------------------------------------------------------------------
__global__ void count_kernel(const int* __restrict__ card, const int* __restrict__ merch,
                             int* cnt_c, int* cnt_m, int n)
{
    int t = blockIdx.x * blockDim.x + threadIdx.x;
    if (t >= n) return;
    atomicAdd(&cnt_c[card[t]], 1);
    atomicAdd(&cnt_m[merch[t]], 1);
}

__global__ void rsqrt_kernel(const int* __restrict__ cnt, float* __restrict__ rs, int n)
{
    int i = blockIdx.x * blockDim.x + threadIdx.x;
    if (i >= n) return;
    int c = cnt[i];
    if (c < 1) c = 1;
    rs[i] = 1.0f / sqrtf((float)c);
}

__global__ __launch_bounds__(1024) void scan_excl(const int* __restrict__ cnt,
                                                  int* __restrict__ off, int n)
{
    __shared__ int wsum[16];
    const int tid = (int)threadIdx.x;
    const int lane = tid & 63, wid = tid >> 6;
    int carry = 0;
    for (int base = 0; base < n; base += 1024) {
        int i = base + tid;
        int v = (i < n) ? cnt[i] : 0;
        int x = v;
        #pragma unroll
        for (int d = 1; d < 64; d <<= 1) {
            int y = __shfl_up(x, d);
            if (lane >= d) x += y;
        }
        if (lane == 63) wsum[wid] = x;
        __syncthreads();
        int wpre = 0, tot = 0;
        #pragma unroll
        for (int w = 0; w < 16; ++w) {
            int s = wsum[w];
            if (w < wid) wpre += s;
            tot += s;
        }
        if (i < n) off[i] = carry + wpre + (x - v);
        carry += tot;
        __syncthreads();
    }
    if (tid == 0) off[n] = carry;
}

__global__ void fill_sorted(const int* __restrict__ ids, const int* __restrict__ off,
                            int* cur, int* __restrict__ srt, int n)
{
    int t = blockIdx.x * blockDim.x + threadIdx.x;
    if (t >= n) return;
    int c = ids[t];
    int p = atomicAdd(&cur[c], 1);
    srt[off[c] + p] = t;
}

// out = hc[card] + hm[merch] + b0 + b1 (+relu); writes fp32 or hi/lo planes
__global__ void gather2_kernel(const float* __restrict__ hc, const float* __restrict__ hm,
                               const int* __restrict__ card, const int* __restrict__ merch,
                               const float* __restrict__ b0, const float* __restrict__ b1,
                               float* __restrict__ out32, _Float16* __restrict__ oh,
                               _Float16* __restrict__ ol, int n, int dim, int relu)
{
    int idx = blockIdx.x * blockDim.x + threadIdx.x;
    int per = dim >> 2;
    int t = idx / per;
    if (t >= n) return;
    int d4 = (idx % per) << 2;
    int c = card[t], m = merch[t];
    float4 a = *(const float4*)(hc + (size_t)c * dim + d4);
    float4 b = *(const float4*)(hm + (size_t)m * dim + d4);
    float4 v0 = *(const float4*)(b0 + d4);
    float4 v1 = *(const float4*)(b1 + d4);
    float4 r;
    r.x = a.x + b.x + v0.x + v1.x;
    r.y = a.y + b.y + v0.y + v1.y;
    r.z = a.z + b.z + v0.z + v1.z;
    r.w = a.w + b.w + v0.w + v1.w;
    if (relu) {
        r.x = fmaxf(r.x, 0.f); r.y = fmaxf(r.y, 0.f);
        r.z = fmaxf(r.z, 0.f); r.w = fmaxf(r.w, 0.f);
    }
    if (out32 != nullptr) {
        *(float4*)(out32 + (size_t)t * dim + d4) = r;
    } else {
        half4v h, l;
        _Float16 th, tl;
        split2(r.x, th, tl); h[0] = th; l[0] = tl;
        split2(r.y, th, tl); h[1] = th; l[1] = tl;
        split2(r.z, th, tl); h[2] = th; l[2] = tl;
        split2(r.w, th, tl); h[3] = th; l[3] = tl;
        *(half4v*)&oh[(size_t)t * dim + d4] = h;
        *(half4v*)&ol[(size_t)t * dim + d4] = l;
    }
}

// CSR aggregate of proj rows (fp32, stride ldp, col offset doff) -> planes
__global__ __launch_bounds__(256) void agg_csr_kernel(
    const float* __restrict__ proj, int ldp, int doff,
    const int* __restrict__ off, const int* __restrict__ srt,
    const float* __restrict__ rs, const float* __restrict__ bias,
    _Float16* __restrict__ oh, _Float16* __restrict__ ol, int n, int relu)
{
    int node = blockIdx.x * 2 + ((int)threadIdx.x >> 7);
    int d = (int)threadIdx.x & 127;
    if (node >= n) return;
    int s = off[node], e = off[node + 1];
    float acc = 0.f;
    for (int i = s; i < e; ++i) {
        int t = srt[i];
        acc += proj[(size_t)t * ldp + doff + d];
    }
    float v = acc * rs[node] + bias[d];
    if (relu) v = fmaxf(v, 0.f);
    _Float16 hh, ll;
    split2(v, hh, ll);
    oh[(size_t)node * 128 + d] = hh;
    ol[(size_t)node * 128 + d] = ll;
}

__global__ __launch_bounds__(256) void dot2_kernel(
    const float* __restrict__ h, const float* __restrict__ w0,
    const float* __restrict__ w1, float* __restrict__ s2, int n)
{
    int row = blockIdx.x * 4 + ((int)threadIdx.x >> 6);
    int l = (int)threadIdx.x & 63;
    if (row >= n) return;
    const float* x = h + (size_t)row * 128;
    float x0 = x[l], x1 = x[l + 64];
    float p0 = x0 * w0[l] + x1 * w0[l + 64];
    float p1 = x0 * w1[l] + x1 * w1[l + 64];
    #pragma unroll
    for (int o = 32; o > 0; o >>= 1) {
        p0 += __shfl_down(p0, o);
        p1 += __shfl_down(p1, o);
    }
    if (l == 0) { s2[(size_t)row * 2] = p0; s2[(size_t)row * 2 + 1] = p1; }
}

__global__ void agg_scalar_kernel(const float* __restrict__ s2, int which,
                                  const int* __restrict__ off, const int* __restrict__ srt,
                                  const float* __restrict__ rs, const float* __restrict__ bias,
                                  float* __restrict__ out, int n)
{
    int node = blockIdx.x * blockDim.x + threadIdx.x;
    if (node >= n) return;
    float acc = 0.f;
    int e = off[node + 1];
    for (int i = off[node]; i < e; ++i) acc += s2[(size_t)srt[i] * 2 + which];
    out[node] = acc * rs[node] + bias[0];
}

// ---------------------------------------------------------------------------
static inline void gemm_ps_launch(const _Float16* Ah, const _Float16* Al,
    const _Float16* Bh, const _Float16* Bl, const float* bias, const float* rs,
    _Float16* Ch, _Float16* Cl, float* C32,
    int M, int Kpad, int N, int relu, hipStream_t s)
{
    const int nbm = (M + 127) / 128;
    if (N % 128 == 0) {
        gemm_ps<2><<<dim3(nbm * (N / 128)), 512, 0, s>>>(
            Ah, Al, Bh, Bl, bias, rs, Ch, Cl, C32, M, Kpad, N, relu);
    } else {
        gemm_ps<1><<<dim3(nbm), 512, 0, s>>>(
            Ah, Al, Bh, Bl, bias, rs, Ch, Cl, C32, M, Kpad, N, relu);
    }
}

#define PAD128(x) ((((x) + 127) / 128) * 128)

extern "C" void kernel_launch(void* const* d_in, const int* in_sizes, int n_in,
                              void* d_out, int out_size, void* d_ws, size_t ws_size,
                              hipStream_t stream)
{
    const float* x_in      = (const float*)d_in[0];
    const int*   card      = (const int*)d_in[1];
    const int*   merch     = (const int*)d_in[2];
    const float* card_emb  = (const float*)d_in[3];
    const float* merch_emb = (const float*)d_in[4];
    const float* pre_Wi = (const float*)d_in[5];
    const float* pre_bi = (const float*)d_in[6];
    const float* pre_Wh = (const float*)d_in[7];
    const float* pre_bh = (const float*)d_in[8];
    const float* pre_Wo = (const float*)d_in[9];
    const float* pre_bo = (const float*)d_in[10];
    const float* conv1_W = (const float*)d_in[11];
    const float* conv1_b = (const float*)d_in[12];
    const float* conv2_W = (const float*)d_in[13];
    const float* conv2_b = (const float*)d_in[14];
    const float* conv3_Wt = (const float*)d_in[15];
    const float* conv3_bt = (const float*)d_in[16];
    const float* conv3_Wo = (const float*)d_in[17];
    const float* conv3_bo = (const float*)d_in[18];
    const float* post_Wi = (const float*)d_in[19];
    const float* post_bi = (const float*)d_in[20];
    const float* post_Wh = (const float*)d_in[21];
    const float* post_bh = (const float*)d_in[22];
    const float* post_Wo = (const float*)d_in[23];
    const float* post_bo = (const float*)d_in[24];

    float* out = (float*)d_out;

    const int MTP = PAD128(NT);
    const int MCP = PAD128(NC);
    const int MMP = PAD128(NM);

    // ---- workspace carve ----
    char* ws = (char*)d_ws;
    size_t off = 0;
    auto alloc = [&](size_t bytes) -> char* {
        char* p = ws + off;
        off += (bytes + 255) & ~(size_t)255;
        return p;
    };
    int* cnt_c = (int*)alloc((size_t)NC * 4);
    int* cnt_m = (int*)alloc((size_t)NM * 4);
    int* cur_c = (int*)alloc((size_t)NC * 4);
    int* cur_m = (int*)alloc((size_t)NM * 4);
    size_t zero_bytes = (size_t)((char*)(cur_m + NM) - (char*)cnt_c);
    int* off_c = (int*)alloc((size_t)(NC + 1) * 4);
    int* off_m = (int*)alloc((size_t)(NM + 1) * 4);
    int* srt_c = (int*)alloc((size_t)NT * 4);
    int* srt_m = (int*)alloc((size_t)NT * 4);
    float* rs_c = (float*)alloc((size_t)NC * 4);
    float* rs_m = (float*)alloc((size_t)NM * 4);

    const int KP_WI = 416;
    _Float16* wi_h  = (_Float16*)alloc((size_t)HPRE * KP_WI * 2);
    _Float16* wi_l  = (_Float16*)alloc((size_t)HPRE * KP_WI * 2);
    _Float16* wh_h  = (_Float16*)alloc((size_t)HPRE * HPRE * 2);
    _Float16* wh_l  = (_Float16*)alloc((size_t)HPRE * HPRE * 2);
    _Float16* wo_h  = (_Float16*)alloc((size_t)DD * HPRE * 2);
    _Float16* wo_l  = (_Float16*)alloc((size_t)DD * HPRE * 2);
    _Float16* c1_h  = (_Float16*)alloc((size_t)4 * DD * DD * 2);
    _Float16* c1_l  = (_Float16*)alloc((size_t)4 * DD * DD * 2);
    _Float16* c2_h  = (_Float16*)alloc((size_t)4 * DD * DD * 2);
    _Float16* c2_l  = (_Float16*)alloc((size_t)4 * DD * DD * 2);
    _Float16* c3_h  = (_Float16*)alloc((size_t)2 * DOUT * DD * 2);
    _Float16* c3_l  = (_Float16*)alloc((size_t)2 * DOUT * DD * 2);
    _Float16* pi_h  = (_Float16*)alloc((size_t)HPOST * DOUT * 2);
    _Float16* pi_l  = (_Float16*)alloc((size_t)HPOST * DOUT * 2);
    _Float16* ph_h  = (_Float16*)alloc((size_t)HPOST * HPOST * 2);
    _Float16* ph_l  = (_Float16*)alloc((size_t)HPOST * HPOST * 2);

    // activation planes
    _Float16* ce_h   = (_Float16*)alloc((size_t)MCP * DD * 2);
    _Float16* ce_l   = (_Float16*)alloc((size_t)MCP * DD * 2);
    _Float16* me_h   = (_Float16*)alloc((size_t)MMP * DD * 2);
    _Float16* me_l   = (_Float16*)alloc((size_t)MMP * DD * 2);
    _Float16* bufA_h = (_Float16*)alloc((size_t)MTP * HPRE * 2);
    _Float16* bufA_l = (_Float16*)alloc((size_t)MTP * HPRE * 2);
    _Float16* bufB_h = (_Float16*)alloc((size_t)MTP * HPRE * 2);
    _Float16* bufB_l = (_Float16*)alloc((size_t)MTP * HPRE * 2);
    _Float16* tf_h   = (_Float16*)alloc((size_t)MTP * DD * 2);
    _Float16* tf_l   = (_Float16*)alloc((size_t)MTP * DD * 2);
    _Float16* h1t_h  = (_Float16*)alloc((size_t)MTP * DD * 2);
    _Float16* h1t_l  = (_Float16*)alloc((size_t)MTP * DD * 2);
    _Float16* h1c_h  = (_Float16*)alloc((size_t)MCP * DD * 2);
    _Float16* h1c_l  = (_Float16*)alloc((size_t)MCP * DD * 2);
    _Float16* h1m_h  = (_Float16*)alloc((size_t)MMP * DD * 2);
    _Float16* h1m_l  = (_Float16*)alloc((size_t)MMP * DD * 2);
    _Float16* h2c_h  = (_Float16*)alloc((size_t)MCP * DD * 2);
    _Float16* h2c_l  = (_Float16*)alloc((size_t)MCP * DD * 2);
    _Float16* h2m_h  = (_Float16*)alloc((size_t)MMP * DD * 2);
    _Float16* h2m_l  = (_Float16*)alloc((size_t)MMP * DD * 2);

    // fp32 buffers
    float* proj = (float*)alloc((size_t)MTP * 256 * 4);   // fused N=256 proj
    float* h2_t = (float*)alloc((size_t)MTP * DD * 4);
    float* hc_p = (float*)alloc((size_t)MCP * DD * 4);
    float* hm_p = (float*)alloc((size_t)MMP * DD * 4);
    float* s2   = (float*)alloc((size_t)NT * 2 * 4);
    (void)ws_size; (void)in_sizes; (void)n_in; (void)out_size;

    // ---- degrees + CSR ----
    hipMemsetAsync(cnt_c, 0, zero_bytes, stream);
    count_kernel<<<(NT + 255) / 256, 256, 0, stream>>>(card, merch, cnt_c, cnt_m, NT);
    rsqrt_kernel<<<(NC + 255) / 256, 256, 0, stream>>>(cnt_c, rs_c, NC);
    rsqrt_kernel<<<(NM + 255) / 256, 256, 0, stream>>>(cnt_m, rs_m, NM);
    scan_excl<<<1, 1024, 0, stream>>>(cnt_c, off_c, NC);
    scan_excl<<<1, 1024, 0, stream>>>(cnt_m, off_m, NM);
    fill_sorted<<<(NT + 255) / 256, 256, 0, stream>>>(card, off_c, cur_c, srt_c, NT);
    fill_sorted<<<(NT + 255) / 256, 256, 0, stream>>>(merch, off_m, cur_m, srt_m, NT);

    // ---- split weights ----
    auto splitw = [&](const float* W, _Float16* h, _Float16* l, int K, int N, int Kpad, int nmat) {
        int total = nmat * N * Kpad;
        split_w<<<(total + 255) / 256, 256, 0, stream>>>(W, h, l, K, N, Kpad, nmat);
    };
    splitw(pre_Wi,   wi_h, wi_l, DIN,  HPRE,  KP_WI, 1);
    splitw(pre_Wh,   wh_h, wh_l, HPRE, HPRE,  HPRE,  1);
    splitw(pre_Wo,   wo_h, wo_l, HPRE, DD,    HPRE,  1);
    splitw(conv1_W,  c1_h, c1_l, DD,   DD,    DD,    4);
    splitw(conv2_W,  c2_h, c2_l, DD,   DD,    DD,    4);
    splitw(conv3_Wt, c3_h, c3_l, DD,   DOUT,  DD,    2);
    splitw(post_Wi,  pi_h, pi_l, DOUT, HPOST, DOUT,  1);
    splitw(post_Wh,  ph_h, ph_l, HPOST,HPOST, HPOST, 1);

    split_a<<<((MCP * (DD / 8)) + 255) / 256, 256, 0, stream>>>(card_emb, ce_h, ce_l, NC, MCP, DD);
    split_a<<<((MMP * (DD / 8)) + 255) / 256, 256, 0, stream>>>(merch_emb, me_h, me_l, NM, MMP, DD);

    const int WP  = DD * DD;
    const int WP3 = DOUT * DD;

    // ---- pre-FF: 390 -> 256 -> 256 -> 128 ----
    {
        const int nbm = (NT + 63) / 64;
        gemm_mfma<1, 2, 2, 2><<<dim3(nbm * 2), 256, 0, stream>>>(
            x_in, wi_h, wi_l, pre_bi, nullptr, nullptr, bufA_h, bufA_l,
            NT, DIN, HPRE, KP_WI, 1);
    }
    gemm_ps_launch(bufA_h, bufA_l, wh_h, wh_l, pre_bh, nullptr,
                   bufB_h, bufB_l, nullptr, NT, HPRE, HPRE, 1, stream);
    gemm_ps_launch(bufB_h, bufB_l, wo_h, wo_l, pre_bo, nullptr,
                   tf_h, tf_l, nullptr, NT, HPRE, DD, 0, stream);

    // ---- conv1 ----
    gemm_ps_launch(ce_h, ce_l, c1_h + 0 * WP, c1_l + 0 * WP, nullptr, rs_c,
                   nullptr, nullptr, hc_p, NC, DD, DD, 0, stream);
    gemm_ps_launch(me_h, me_l, c1_h + 1 * WP, c1_l + 1 * WP, nullptr, rs_m,
                   nullptr, nullptr, hm_p, NM, DD, DD, 0, stream);
    gather2_kernel<<<(NT * (DD / 4) + 255) / 256, 256, 0, stream>>>(
        hc_p, hm_p, card, merch, conv1_b, conv1_b + DD,
        nullptr, h1t_h, h1t_l, NT, DD, 1);
    // fused t->card | t->merch projection (N=256, contiguous weight planes)
    gemm_ps_launch(tf_h, tf_l, c1_h + 2 * WP, c1_l + 2 * WP, nullptr, nullptr,
                   nullptr, nullptr, proj, NT, DD, 256, 0, stream);
    agg_csr_kernel<<<(NC + 1) / 2, 256, 0, stream>>>(proj, 256, 0, off_c, srt_c, rs_c,
                                                     conv1_b + 2 * DD, h1c_h, h1c_l, NC, 1);
    agg_csr_kernel<<<(NM + 1) / 2, 256, 0, stream>>>(proj, 256, 128, off_m, srt_m, rs_m,
                                                     conv1_b + 3 * DD, h1m_h, h1m_l, NM, 1);

    // ---- conv2 ----
    gemm_ps_launch(h1c_h, h1c_l, c2_h + 0 * WP, c2_l + 0 * WP, nullptr, rs_c,
                   nullptr, nullptr, hc_p, NC, DD, DD, 0, stream);
    gemm_ps_launch(h1m_h, h1m_l, c2_h + 1 * WP, c2_l + 1 * WP, nullptr, rs_m,
                   nullptr, nullptr, hm_p, NM, DD, DD, 0, stream);
    gather2_kernel<<<(NT * (DD / 4) + 255) / 256, 256, 0, stream>>>(
        hc_p, hm_p, card, merch, conv2_b, conv2_b + DD,
        h2_t, nullptr, nullptr, NT, DD, 1);
    gemm_ps_launch(h1t_h, h1t_l, c2_h + 2 * WP, c2_l + 2 * WP, nullptr, nullptr,
                   nullptr, nullptr, proj, NT, DD, 256, 0, stream);
    agg_csr_kernel<<<(NC + 1) / 2, 256, 0, stream>>>(proj, 256, 0, off_c, srt_c, rs_c,
                                                     conv2_b + 2 * DD, h2c_h, h2c_l, NC, 1);
    agg_csr_kernel<<<(NM + 1) / 2, 256, 0, stream>>>(proj, 256, 128, off_m, srt_m, rs_m,
                                                     conv2_b + 3 * DD, h2m_h, h2m_l, NM, 1);

    // ---- conv3 ----
    gemm_ps_launch(h2c_h, h2c_l, c3_h + 0 * WP3, c3_l + 0 * WP3, nullptr, rs_c,
                   nullptr, nullptr, hc_p, NC, DD, DOUT, 0, stream);
    gemm_ps_launch(h2m_h, h2m_l, c3_h + 1 * WP3, c3_l + 1 * WP3, nullptr, rs_m,
                   nullptr, nullptr, hm_p, NM, DD, DOUT, 0, stream);
    dot2_kernel<<<(NT + 3) / 4, 256, 0, stream>>>(h2_t, conv3_Wo, conv3_Wo + DD, s2, NT);
    agg_scalar_kernel<<<(NC + 255) / 256, 256, 0, stream>>>(s2, 0, off_c, srt_c, rs_c,
                                                            conv3_bo + 0, out + NT, NC);
    agg_scalar_kernel<<<(NM + 255) / 256, 256, 0, stream>>>(s2, 1, off_m, srt_m, rs_m,
                                                            conv3_bo + 1, out + NT + NC, NM);

    // ---- fused post-FF: gather + 64 -> 64 -> 64 -> 1 ----
    post_ff<<<dim3((NT + 127) / 128), 512, 0, stream>>>(
        hc_p, hm_p, card, merch, conv3_bt, conv3_bt + DOUT,
        pi_h, pi_l, post_bi, ph_h, ph_l, post_bh, post_Wo, post_bo, out, NT);
}

// Round 5
// 2492.297 us; speedup vs baseline: 1.1217x; 1.1217x over previous
//
#include <hip/hip_runtime.h>

// EnhancedRGCN on MI355X — split-f16 MFMA GEMMs (fp32-accurate via hi/lo
// decomposition, 3 MFMA terms), CSR-gather aggregations, fp32 elementwise.
//
// x = hi + lo/512, hi=f16(x), lo=f16((x-hi)*512). A@W = hiA@hiW +
// (hiA@loW + loA@hiW)/512; cross terms share one accumulator.
//
// Round 5:
//  - PRE-AGGREGATION (linearity): agg(tf @ W) = (agg tf) @ W for t->card /
//    t->merch GraphConvs (d_t = 1). The 300k-row projection GEMMs + proj
//    buffer traffic become CSR-sum passes + 100k/20k-row GEMMs.
//  - gemm_ps reverted to 64 KB double-buffer (r3, 2 blocks/CU) keeping the
//    r4 swizzle key (4-way instead of 8-way read conflicts).
//  - FF1 reverted to depth-1 register prefetch (r4 depth-2 regressed).
//  - post_ff fusion kept.

#define NT 300000
#define NC 100000
#define NM 20000
#define DIN 390
#define DD 128
#define DOUT 64
#define HPRE 256
#define HPOST 64

typedef _Float16 half8 __attribute__((ext_vector_type(8)));
typedef _Float16 half4v __attribute__((ext_vector_type(4)));
typedef float f32x16 __attribute__((ext_vector_type(16)));
typedef float f32x4 __attribute__((ext_vector_type(4)));

#define LO_SCALE 512.0f
#define LO_INV   (1.0f / 512.0f)

__device__ __forceinline__ void split2(float x, _Float16& h, _Float16& l) {
    _Float16 hh = (_Float16)x;
    h = hh;
    l = (_Float16)((x - (float)hh) * LO_SCALE);
}

__device__ __forceinline__ void gload16(const _Float16* g, _Float16* l) {
    __builtin_amdgcn_global_load_lds(
        (const __attribute__((address_space(1))) void*)g,
        (__attribute__((address_space(3))) void*)l, 16, 0, 0);
}

// ---------------------------------------------------------------------------
// gemm_ps: C = act((A@W) * rowscale + bias), A pre-split hi/lo planes
// [Mpad][Kpad] f16, W pre-split planes [N][Kpad] f16. BM=128, BN=64*TN.
// 512 threads (8 waves). Double-buffered LDS (64 KB -> 2 blocks/CU),
// counted vmcnt so next-tile loads stay in flight across barriers.
// Swizzle: phys 16B-chunk = logical ^ ((row>>1)&3), linear DMA dest,
// inverse-swizzled global source (both-sides-or-neither).
// ---------------------------------------------------------------------------
template<int TN>
__global__ __launch_bounds__(512, 4) void gemm_ps(
    const _Float16* __restrict__ Agh, const _Float16* __restrict__ Agl,
    const _Float16* __restrict__ Bgh, const _Float16* __restrict__ Bgl,
    const float* __restrict__ bias, const float* __restrict__ rowscale,
    _Float16* __restrict__ Ch, _Float16* __restrict__ Cl,
    float* __restrict__ C32,
    int M, int Kpad, int N, int relu)
{
    constexpr int BM = 128;
    constexpr int BN = 64 * TN;
    constexpr int OFF_AL = 4096;           // halves (128 rows x 32)
    constexpr int OFF_BH = 8192;
    constexpr int OFF_BL = 8192 + BN * 32;
    constexpr int BUFH   = 8192 + 2 * BN * 32;   // halves per buffer
    constexpr int NLD    = (TN == 2) ? 4 : 3;    // gload_lds per thread/stage
    __shared__ __align__(16) _Float16 smem[2 * BUFH];

    const int tid  = (int)threadIdx.x;
    const int lane = tid & 63;
    const int wave = tid >> 6;
    const int wm0  = (wave & 3) * 32;
    const int wn0  = (wave >> 2) * 32 * TN;

    const int nbn  = N / BN;
    const int bm   = ((int)blockIdx.x / nbn) * BM;
    const int bn   = ((int)blockIdx.x % nbn) * BN;

    // staging: 16B per thread per plane; source pre-swizzled
    const int srow = lane >> 2;                                  // 0..15
    const int xc8  = (((lane & 3) ^ ((srow >> 1) & 3)) << 3);    // k halves
    const size_t a_off = (size_t)(bm + wave * 16 + srow) * Kpad + xc8;
    size_t b_off;
    if constexpr (TN == 2) {
        b_off = (size_t)(bn + wave * 16 + srow) * Kpad + xc8;
    } else {
        b_off = (size_t)(bn + (wave & 3) * 16 + srow) * Kpad + xc8;
    }

    auto stage = [&](int b, int k0) {
        _Float16* sb = &smem[b * BUFH];
        gload16(Agh + a_off + k0, sb + wave * 512);
        gload16(Agl + a_off + k0, sb + OFF_AL + wave * 512);
        if constexpr (TN == 2) {
            gload16(Bgh + b_off + k0, sb + OFF_BH + wave * 512);
            gload16(Bgl + b_off + k0, sb + OFF_BL + wave * 512);
        } else {
            gload16((wave < 4 ? Bgh : Bgl) + b_off + k0,
                    sb + (wave < 4 ? OFF_BH : OFF_BL) + (wave & 3) * 512);
        }
    };

    f32x16 zz;
    #pragma unroll
    for (int i = 0; i < 16; ++i) zz[i] = 0.f;
    f32x16 acc_hh[TN], acc_x[TN];
    #pragma unroll
    for (int t2 = 0; t2 < TN; ++t2) { acc_hh[t2] = zz; acc_x[t2] = zz; }

    const int mlr = lane & 31;          // MFMA m/n index
    const int hi5 = lane >> 5;          // k sub-group
    const int xr  = (mlr >> 1) & 3;     // read-side swizzle key

    const int NS = Kpad >> 5;
    stage(0, 0);

    for (int t = 0; t < NS; ++t) {
        if (t + 1 < NS) {
            stage((t + 1) & 1, (t + 1) << 5);
            asm volatile("s_waitcnt vmcnt(%0)" :: "n"(NLD) : "memory");
        } else {
            asm volatile("s_waitcnt vmcnt(0)" ::: "memory");
        }
        __builtin_amdgcn_s_barrier();
        __builtin_amdgcn_sched_barrier(0);

        const _Float16* sb = &smem[(t & 1) * BUFH];
        #pragma unroll
        for (int ks = 0; ks < 2; ++ks) {
            const int xo = (((ks * 2 + hi5) ^ xr) << 3);
            const half8 fah = *(const half8*)&sb[(wm0 + mlr) * 32 + xo];
            const half8 fal = *(const half8*)&sb[OFF_AL + (wm0 + mlr) * 32 + xo];
            half8 fbh[TN], fbl[TN];
            #pragma unroll
            for (int t2 = 0; t2 < TN; ++t2) {
                const int nn = wn0 + t2 * 32 + mlr;
                fbh[t2] = *(const half8*)&sb[OFF_BH + nn * 32 + xo];
                fbl[t2] = *(const half8*)&sb[OFF_BL + nn * 32 + xo];
            }
            #pragma unroll
            for (int t2 = 0; t2 < TN; ++t2) {
                acc_hh[t2] = __builtin_amdgcn_mfma_f32_32x32x16_f16(
                    fah, fbh[t2], acc_hh[t2], 0, 0, 0);
                acc_x[t2] = __builtin_amdgcn_mfma_f32_32x32x16_f16(
                    fah, fbl[t2], acc_x[t2], 0, 0, 0);
                acc_x[t2] = __builtin_amdgcn_mfma_f32_32x32x16_f16(
                    fal, fbh[t2], acc_x[t2], 0, 0, 0);
            }
        }
        __builtin_amdgcn_sched_barrier(0);
        __builtin_amdgcn_s_barrier();
    }

    // ---- epilogue ----
    const int r0 = 4 * hi5;
    #pragma unroll
    for (int t2 = 0; t2 < TN; ++t2) {
        const int gcol = bn + wn0 + t2 * 32 + mlr;
        const float bc = (bias != nullptr) ? bias[gcol] : 0.f;
        #pragma unroll
        for (int r = 0; r < 16; ++r) {
            const int grow = bm + wm0 + (r & 3) + r0 + 8 * (r >> 2);
            if (grow < M) {
                float v = acc_hh[t2][r] + acc_x[t2][r] * LO_INV;
                if (rowscale != nullptr) v *= rowscale[grow];
                v += bc;
                if (relu) v = fmaxf(v, 0.f);
                if (C32 != nullptr) {
                    C32[(size_t)grow * N + gcol] = v;
                } else {
                    _Float16 hh, ll;
                    split2(v, hh, ll);
                    Ch[(size_t)grow * N + gcol] = hh;
                    Cl[(size_t)grow * N + gcol] = ll;
                }
            }
        }
    }
}

// ---------------------------------------------------------------------------
// Register-split GEMM for FF1 (A = raw fp32 input). BM=64, BN=128,
// 256 threads, depth-1 register prefetch. Epilogue emits fp32 or planes.
// ---------------------------------------------------------------------------
template<int TM, int TN, int WGM, int WGN>
__global__ __launch_bounds__(256, 3) void gemm_mfma(
    const float* __restrict__ A, const _Float16* __restrict__ Wh,
    const _Float16* __restrict__ Wl, const float* __restrict__ bias,
    const float* __restrict__ rowscale,
    float* __restrict__ C32, _Float16* __restrict__ Ch, _Float16* __restrict__ Cl,
    int M, int K, int N, int Kpad, int relu)
{
    constexpr int BM = 32 * TM * WGM;
    constexpr int BN = 32 * TN * WGN;
    constexpr int RS = 40;
    __shared__ __align__(16) _Float16 Ah[BM * RS];
    __shared__ __align__(16) _Float16 Al[BM * RS];
    __shared__ __align__(16) _Float16 Bh[BN * RS];
    __shared__ __align__(16) _Float16 Bl[BN * RS];

    const int tid  = (int)threadIdx.x;
    const int lane = tid & 63;
    const int wave = tid >> 6;
    const int wm0 = (wave % WGM) * 32 * TM;
    const int wn0 = (wave / WGM) * 32 * TN;

    const int nbn = N / BN;
    const int tile = (int)blockIdx.x;
    const int bm = (tile / nbn) * BM;
    const int bn = (tile % nbn) * BN;

    f32x16 zz;
    #pragma unroll
    for (int i = 0; i < 16; ++i) zz[i] = 0.f;
    f32x16 acc_hh[TM][TN], acc_x[TM][TN];
    #pragma unroll
    for (int tm = 0; tm < TM; ++tm)
        #pragma unroll
        for (int tn = 0; tn < TN; ++tn) { acc_hh[tm][tn] = zz; acc_x[tm][tn] = zz; }

    constexpr int TPR  = 256 / BM;
    constexpr int KPT  = 32 / TPR;
    constexpr int FQ   = KPT / 4;
    const int sar = tid / TPR;
    const int sak = (tid % TPR) * KPT;
    const int agrow = bm + sar;
    const float* Aptr = A + (size_t)agrow * K;

    constexpr int TPRB = 256 / BN;
    constexpr int KPTB = 32 / TPRB;
    constexpr int NB   = KPTB / 8;
    const int sbr = tid / TPRB;
    const int sbk = (tid % TPRB) * KPTB;
    const _Float16* Bhp = Wh + (size_t)(bn + sbr) * Kpad + sbk;
    const _Float16* Blp = Wl + (size_t)(bn + sbr) * Kpad + sbk;

    const int ml  = lane & 31;
    const int klo = (lane >> 5) * 8;

    f32x4 areg[FQ];
    half8 bhreg[NB], blreg[NB];

    auto loadA = [&](int k0) {
        #pragma unroll
        for (int q = 0; q < FQ; ++q) {
            const int kb = k0 + sak + q * 4;
            f32x4 f = {0.f, 0.f, 0.f, 0.f};
            if (agrow < M) {
                if (kb + 3 < K) {
                    f = *(const f32x4*)(Aptr + kb);
                } else {
                    if (kb + 0 < K) f[0] = Aptr[kb + 0];
                    if (kb + 1 < K) f[1] = Aptr[kb + 1];
                    if (kb + 2 < K) f[2] = Aptr[kb + 2];
                    if (kb + 3 < K) f[3] = Aptr[kb + 3];
                }
            }
            areg[q] = f;
        }
    };
    auto loadB = [&](int k0) {
        #pragma unroll
        for (int j = 0; j < NB; ++j) {
            bhreg[j] = *(const half8*)(Bhp + k0 + j * 8);
            blreg[j] = *(const half8*)(Blp + k0 + j * 8);
        }
    };

    loadA(0);
    loadB(0);

    for (int k0 = 0; k0 < K; k0 += 32) {
        #pragma unroll
        for (int c = 0; c < FQ / 2; ++c) {
            half8 h, l;
            #pragma unroll
            for (int q = 0; q < 2; ++q) {
                #pragma unroll
                for (int j = 0; j < 4; ++j) {
                    _Float16 th, tl;
                    split2(areg[2 * c + q][j], th, tl);
                    h[q * 4 + j] = th;
                    l[q * 4 + j] = tl;
                }
            }
            *(half8*)&Ah[sar * RS + sak + c * 8] = h;
            *(half8*)&Al[sar * RS + sak + c * 8] = l;
        }
        #pragma unroll
        for (int j = 0; j < NB; ++j) {
            *(half8*)&Bh[sbr * RS + sbk + j * 8] = bhreg[j];
            *(half8*)&Bl[sbr * RS + sbk + j * 8] = blreg[j];
        }
        __syncthreads();

        if (k0 + 32 < K) { loadA(k0 + 32); loadB(k0 + 32); }

        #pragma unroll
        for (int ks = 0; ks < 2; ++ks) {
            const int kk = ks * 16 + klo;
            half8 fah[TM], fal[TM], fbh[TN], fbl[TN];
            #pragma unroll
            for (int t = 0; t < TM; ++t) {
                const int m = wm0 + t * 32 + ml;
                fah[t] = *(const half8*)&Ah[m * RS + kk];
                fal[t] = *(const half8*)&Al[m * RS + kk];
            }
            #pragma unroll
            for (int t = 0; t < TN; ++t) {
                const int n = wn0 + t * 32 + ml;
                fbh[t] = *(const half8*)&Bh[n * RS + kk];
                fbl[t] = *(const half8*)&Bl[n * RS + kk];
            }
            #pragma unroll
            for (int tm = 0; tm < TM; ++tm)
                #pragma unroll
                for (int tn = 0; tn < TN; ++tn) {
                    acc_hh[tm][tn] = __builtin_amdgcn_mfma_f32_32x32x16_f16(
                        fah[tm], fbh[tn], acc_hh[tm][tn], 0, 0, 0);
                    acc_x[tm][tn] = __builtin_amdgcn_mfma_f32_32x32x16_f16(
                        fah[tm], fbl[tn], acc_x[tm][tn], 0, 0, 0);
                    acc_x[tm][tn] = __builtin_amdgcn_mfma_f32_32x32x16_f16(
                        fal[tm], fbh[tn], acc_x[tm][tn], 0, 0, 0);
                }
        }
        __syncthreads();
    }

    const int r0 = 4 * (lane >> 5);
    #pragma unroll
    for (int tm = 0; tm < TM; ++tm) {
        #pragma unroll
        for (int tn = 0; tn < TN; ++tn) {
            const int gcol = bn + wn0 + tn * 32 + ml;
            const float bc = (bias != nullptr) ? bias[gcol] : 0.f;
            #pragma unroll
            for (int r = 0; r < 16; ++r) {
                const int grow = bm + wm0 + tm * 32 + (r & 3) + r0 + 8 * (r >> 2);
                if (grow < M) {
                    float v = acc_hh[tm][tn][r] + acc_x[tm][tn][r] * LO_INV;
                    if (rowscale != nullptr) v *= rowscale[grow];
                    v += bc;
                    if (relu) v = fmaxf(v, 0.f);
                    if (C32 != nullptr) {
                        C32[(size_t)grow * N + gcol] = v;
                    } else {
                        _Float16 hh, ll;
                        split2(v, hh, ll);
                        Ch[(size_t)grow * N + gcol] = hh;
                        Cl[(size_t)grow * N + gcol] = ll;
                    }
                }
            }
        }
    }
}

// ---------------------------------------------------------------------------
// Fused post-FF: gather h3 = hc[card]+hm[merch]+bt0+bt1, then
// h=relu(h3@Wi+bi) -> h=relu(h@Wh+bh) -> out=h@Wo+bo. LDS-resident.
// ---------------------------------------------------------------------------
__global__ __launch_bounds__(512, 2) void post_ff(
    const float* __restrict__ hc, const float* __restrict__ hm,
    const int* __restrict__ card, const int* __restrict__ merch,
    const float* __restrict__ bt0, const float* __restrict__ bt1,
    const _Float16* __restrict__ wih, const _Float16* __restrict__ wil,
    const float* __restrict__ bi,
    const _Float16* __restrict__ whh, const _Float16* __restrict__ whl,
    const float* __restrict__ bh,
    const float* __restrict__ wo, const float* __restrict__ bo,
    float* __restrict__ out, int n)
{
    constexpr int SR = 72;
    constexpr int OFF_AH = 0;
    constexpr int OFF_AL = 9216;
    constexpr int OFF_HH = 18432;
    constexpr int OFF_HL = 27648;
    constexpr int OFF_W1H = 36864;
    constexpr int OFF_W1L = 41472;
    constexpr int OFF_W2H = 46080;
    constexpr int OFF_W2L = 50688;
    __shared__ __align__(16) _Float16 S[55296];   // 108 KB
    float* sh2 = (float*)&S[OFF_AH];

    const int tid  = (int)threadIdx.x;
    const int lane = tid & 63;
    const int wave = tid >> 6;
    const int bm   = (int)blockIdx.x * 128;

    // ---- stage W planes ----
    {
        const int wn = (tid & 255) >> 2;
        const int c0 = (tid & 3) * 16;
        const _Float16* gh = (tid < 256) ? wih : whh;
        const _Float16* gl = (tid < 256) ? wil : whl;
        const int oh = (tid < 256) ? OFF_W1H : OFF_W2H;
        const int ol = (tid < 256) ? OFF_W1L : OFF_W2L;
        *(half8*)&S[oh + wn * SR + c0]     = *(const half8*)(gh + wn * 64 + c0);
        *(half8*)&S[oh + wn * SR + c0 + 8] = *(const half8*)(gh + wn * 64 + c0 + 8);
        *(half8*)&S[ol + wn * SR + c0]     = *(const half8*)(gl + wn * 64 + c0);
        *(half8*)&S[ol + wn * SR + c0 + 8] = *(const half8*)(gl + wn * 64 + c0 + 8);
    }
    // ---- gather + split A ----
    {
        const int r  = tid >> 2;
        const int c0 = (tid & 3) << 4;
        const int t  = bm + r;
        const bool ok = (t < n);
        const int ci = ok ? card[t] : 0;
        const int mi = ok ? merch[t] : 0;
        #pragma unroll
        for (int q = 0; q < 4; ++q) {
            const int c = c0 + q * 4;
            float4 a = make_float4(0.f, 0.f, 0.f, 0.f);
            if (ok) {
                float4 va = *(const float4*)(hc + (size_t)ci * 64 + c);
                float4 vb = *(const float4*)(hm + (size_t)mi * 64 + c);
                float4 b0 = *(const float4*)(bt0 + c);
                float4 b1 = *(const float4*)(bt1 + c);
                a.x = va.x + vb.x + b0.x + b1.x;
                a.y = va.y + vb.y + b0.y + b1.y;
                a.z = va.z + vb.z + b0.z + b1.z;
                a.w = va.w + vb.w + b0.w + b1.w;
            }
            half4v h, l;
            _Float16 th, tl;
            split2(a.x, th, tl); h[0] = th; l[0] = tl;
            split2(a.y, th, tl); h[1] = th; l[1] = tl;
            split2(a.z, th, tl); h[2] = th; l[2] = tl;
            split2(a.w, th, tl); h[3] = th; l[3] = tl;
            *(half4v*)&S[OFF_AH + r * SR + c] = h;
            *(half4v*)&S[OFF_AL + r * SR + c] = l;
        }
    }
    __syncthreads();

    const int mlr = lane & 31;
    const int hi5 = lane >> 5;
    const int wm = (wave & 3) * 32;
    const int wn = (wave >> 2) * 32;
    const int r0 = 4 * hi5;

    f32x16 zz;
    #pragma unroll
    for (int i = 0; i < 16; ++i) zz[i] = 0.f;

    // ---- layer 1 ----
    {
        f32x16 acc = zz, accx = zz;
        #pragma unroll
        for (int ks = 0; ks < 4; ++ks) {
            const int kk = ks * 16 + hi5 * 8;
            const half8 fah = *(const half8*)&S[OFF_AH + (wm + mlr) * SR + kk];
            const half8 fal = *(const half8*)&S[OFF_AL + (wm + mlr) * SR + kk];
            const half8 fbh = *(const half8*)&S[OFF_W1H + (wn + mlr) * SR + kk];
            const half8 fbl = *(const half8*)&S[OFF_W1L + (wn + mlr) * SR + kk];
            acc  = __builtin_amdgcn_mfma_f32_32x32x16_f16(fah, fbh, acc, 0, 0, 0);
            accx = __builtin_amdgcn_mfma_f32_32x32x16_f16(fah, fbl, accx, 0, 0, 0);
            accx = __builtin_amdgcn_mfma_f32_32x32x16_f16(fal, fbh, accx, 0, 0, 0);
        }
        const float bc = bi[wn + mlr];
        __syncthreads();
        #pragma unroll
        for (int r = 0; r < 16; ++r) {
            const int row = wm + (r & 3) + r0 + 8 * (r >> 2);
            float v = acc[r] + accx[r] * LO_INV + bc;
            v = fmaxf(v, 0.f);
            _Float16 hh, ll;
            split2(v, hh, ll);
            S[OFF_HH + row * SR + wn + mlr] = hh;
            S[OFF_HL + row * SR + wn + mlr] = ll;
        }
    }
    __syncthreads();

    // ---- layer 2 ----
    {
        f32x16 acc = zz, accx = zz;
        #pragma unroll
        for (int ks = 0; ks < 4; ++ks) {
            const int kk = ks * 16 + hi5 * 8;
            const half8 fah = *(const half8*)&S[OFF_HH + (wm + mlr) * SR + kk];
            const half8 fal = *(const half8*)&S[OFF_HL + (wm + mlr) * SR + kk];
            const half8 fbh = *(const half8*)&S[OFF_W2H + (wn + mlr) * SR + kk];
            const half8 fbl = *(const half8*)&S[OFF_W2L + (wn + mlr) * SR + kk];
            acc  = __builtin_amdgcn_mfma_f32_32x32x16_f16(fah, fbh, acc, 0, 0, 0);
            accx = __builtin_amdgcn_mfma_f32_32x32x16_f16(fah, fbl, accx, 0, 0, 0);
            accx = __builtin_amdgcn_mfma_f32_32x32x16_f16(fal, fbh, accx, 0, 0, 0);
        }
        const float bc = bh[wn + mlr];
        __syncthreads();
        #pragma unroll
        for (int r = 0; r < 16; ++r) {
            const int row = wm + (r & 3) + r0 + 8 * (r >> 2);
            float v = acc[r] + accx[r] * LO_INV + bc;
            sh2[row * 68 + wn + mlr] = fmaxf(v, 0.f);
        }
    }
    __syncthreads();

    // ---- output ----
    if (tid < 128) {
        const int t = bm + tid;
        if (t < n) {
            float s = bo[0];
            #pragma unroll 8
            for (int c = 0; c < 64; ++c) s += sh2[tid * 68 + c] * wo[c];
            out[t] = s;
        }
    }
}

// W[e][k][n] fp32 -> hiT/loT [e][n][Kpad] f16 planes (zero-padded K -> Kpad)
__global__ void split_w(const float* __restrict__ W, _Float16* __restrict__ hiT,
                        _Float16* __restrict__ loT, int K, int N, int Kpad, int nmat)
{
    int idx = blockIdx.x * blockDim.x + threadIdx.x;
    int total = nmat * N * Kpad;
    if (idx >= total) return;
    int e = idx / (N * Kpad);
    int rem = idx - e * (N * Kpad);
    int n = rem / Kpad;
    int k = rem - n * Kpad;
    float v = (k < K) ? W[((size_t)e * K + k) * N + n] : 0.f;
    _Float16 h = (_Float16)v;
    hiT[idx] = h;
    loT[idx] = (_Float16)((v - (float)h) * LO_SCALE);
}

// X[M][K] fp32 row-major -> hi/lo planes [Mpad][K], pad rows zero
__global__ void split_a(const float* __restrict__ X, _Float16* __restrict__ xh,
                        _Float16* __restrict__ xl, int M, int Mpad, int K)
{
    int idx = blockIdx.x * blockDim.x + threadIdx.x;
    int per = K >> 3;
    int total = Mpad * per;
    if (idx >= total) return;
    int row = idx / per;
    int k = (idx - row * per) << 3;
    half8 h, l;
    if (row < M) {
        #pragma unroll
        for (int j = 0; j < 8; ++j) {
            _Float16 th, tl;
            split2(X[(size_t)row * K + k + j], th, tl);
            h[j] = th; l[j] = tl;
        }
    } else {
        #pragma unroll
        for (int j = 0; j < 8; ++j) { h[j] = (_Float16)0.f; l[j] = (_Float16)0.f; }
    }
    *(half8*)&xh[(size_t)row * K + k] = h;
    *(half8*)&xl[(size_t)row * K + k] = l;
}

// ---------------------------------------------------------------------------
// Graph helper kernels
// ---------------------------------------------------------------------------
__global__ void count_kernel(const int* __restrict__ card, const int* __restrict__ merch,
                             int* cnt_c, int* cnt_m, int n)
{
    int t = blockIdx.x * blockDim.x + threadIdx.x;
    if (t >= n) return;
    atomicAdd(&cnt_c[card[t]], 1);
    atomicAdd(&cnt_m[merch[t]], 1);
}

__global__ void rsqrt_kernel(const int* __restrict__ cnt, float* __restrict__ rs, int n)
{
    int i = blockIdx.x * blockDim.x + threadIdx.x;
    if (i >= n) return;
    int c = cnt[i];
    if (c < 1) c = 1;
    rs[i] = 1.0f / sqrtf((float)c);
}

__global__ __launch_bounds__(1024) void scan_excl(const int* __restrict__ cnt,
                                                  int* __restrict__ off, int n)
{
    __shared__ int wsum[16];
    const int tid = (int)threadIdx.x;
    const int lane = tid & 63, wid = tid >> 6;
    int carry = 0;
    for (int base = 0; base < n; base += 1024) {
        int i = base + tid;
        int v = (i < n) ? cnt[i] : 0;
        int x = v;
        #pragma unroll
        for (int d = 1; d < 64; d <<= 1) {
            int y = __shfl_up(x, d);
            if (lane >= d) x += y;
        }
        if (lane == 63) wsum[wid] = x;
        __syncthreads();
        int wpre = 0, tot = 0;
        #pragma unroll
        for (int w = 0; w < 16; ++w) {
            int s = wsum[w];
            if (w < wid) wpre += s;
            tot += s;
        }
        if (i < n) off[i] = carry + wpre + (x - v);
        carry += tot;
        __syncthreads();
    }
    if (tid == 0) off[n] = carry;
}

__global__ void fill_sorted(const int* __restrict__ ids, const int* __restrict__ off,
                            int* cur, int* __restrict__ srt, int n)
{
    int t = blockIdx.x * blockDim.x + threadIdx.x;
    if (t >= n) return;
    int c = ids[t];
    int p = atomicAdd(&cur[c], 1);
    srt[off[c] + p] = t;
}

// out = hc[card] + hm[merch] + b0 + b1 (+relu), fp32
__global__ void gather2_kernel(const float* __restrict__ hc, const float* __restrict__ hm,
                               const int* __restrict__ card, const int* __restrict__ merch,
                               const float* __restrict__ b0, const float* __restrict__ b1,
                               float* __restrict__ out, int n, int dim, int relu)
{
    int idx = blockIdx.x * blockDim.x + threadIdx.x;
    int per = dim >> 2;
    int t = idx / per;
    if (t >= n) return;
    int d4 = (idx % per) << 2;
    int c = card[t], m = merch[t];
    float4 a = *(const float4*)(hc + (size_t)c * dim + d4);
    float4 b = *(const float4*)(hm + (size_t)m * dim + d4);
    float4 v0 = *(const float4*)(b0 + d4);
    float4 v1 = *(const float4*)(b1 + d4);
    float4 r;
    r.x = a.x + b.x + v0.x + v1.x;
    r.y = a.y + b.y + v0.y + v1.y;
    r.z = a.z + b.z + v0.z + v1.z;
    r.w = a.w + b.w + v0.w + v1.w;
    if (relu) {
        r.x = fmaxf(r.x, 0.f); r.y = fmaxf(r.y, 0.f);
        r.z = fmaxf(r.z, 0.f); r.w = fmaxf(r.w, 0.f);
    }
    *(float4*)(out + (size_t)t * dim + d4) = r;
}

// Raw CSR pre-aggregation: planes(sum of src rows). No scale/bias/relu
// (they move into the following GEMM). Linearity: agg(X @ W) = agg(X) @ W.
__global__ __launch_bounds__(256) void agg_raw_kernel(
    const float* __restrict__ src, const int* __restrict__ off,
    const int* __restrict__ srt, _Float16* __restrict__ oh,
    _Float16* __restrict__ ol, int n)
{
    int node = blockIdx.x * 2 + ((int)threadIdx.x >> 7);
    int d = (int)threadIdx.x & 127;
    if (node >= n) return;
    int s = off[node], e = off[node + 1];
    float acc = 0.f;
    for (int i = s; i < e; ++i)
        acc += src[(size_t)srt[i] * 128 + d];
    _Float16 hh, ll;
    split2(acc, hh, ll);
    oh[(size_t)node * 128 + d] = hh;
    ol[(size_t)node * 128 + d] = ll;
}

__global__ __launch_bounds__(256) void dot2_kernel(
    const float* __restrict__ h, const float* __restrict__ w0,
    const float* __restrict__ w1, float* __restrict__ s2, int n)
{
    int row = blockIdx.x * 4 + ((int)threadIdx.x >> 6);
    int l = (int)threadIdx.x & 63;
    if (row >= n) return;
    const float* x = h + (size_t)row * 128;
    float x0 = x[l], x1 = x[l + 64];
    float p0 = x0 * w0[l] + x1 * w0[l + 64];
    float p1 = x0 * w1[l] + x1 * w1[l + 64];
    #pragma unroll
    for (int o = 32; o > 0; o >>= 1) {
        p0 += __shfl_down(p0, o);
        p1 += __shfl_down(p1, o);
    }
    if (l == 0) { s2[(size_t)row * 2] = p0; s2[(size_t)row * 2 + 1] = p1; }
}

__global__ void agg_scalar_kernel(const float* __restrict__ s2, int which,
                                  const int* __restrict__ off, const int* __restrict__ srt,
                                  const float* __restrict__ rs, const float* __restrict__ bias,
                                  float* __restrict__ out, int n)
{
    int node = blockIdx.x * blockDim.x + threadIdx.x;
    if (node >= n) return;
    float acc = 0.f;
    int e = off[node + 1];
    for (int i = off[node]; i < e; ++i) acc += s2[(size_t)srt[i] * 2 + which];
    out[node] = acc * rs[node] + bias[0];
}

// ---------------------------------------------------------------------------
static inline void gemm_ps_launch(const _Float16* Ah, const _Float16* Al,
    const _Float16* Bh, const _Float16* Bl, const float* bias, const float* rs,
    _Float16* Ch, _Float16* Cl, float* C32,
    int M, int Kpad, int N, int relu, hipStream_t s)
{
    const int nbm = (M + 127) / 128;
    if (N % 128 == 0) {
        gemm_ps<2><<<dim3(nbm * (N / 128)), 512, 0, s>>>(
            Ah, Al, Bh, Bl, bias, rs, Ch, Cl, C32, M, Kpad, N, relu);
    } else {
        gemm_ps<1><<<dim3(nbm), 512, 0, s>>>(
            Ah, Al, Bh, Bl, bias, rs, Ch, Cl, C32, M, Kpad, N, relu);
    }
}

#define PAD128(x) ((((x) + 127) / 128) * 128)

extern "C" void kernel_launch(void* const* d_in, const int* in_sizes, int n_in,
                              void* d_out, int out_size, void* d_ws, size_t ws_size,
                              hipStream_t stream)
{
    const float* x_in      = (const float*)d_in[0];
    const int*   card      = (const int*)d_in[1];
    const int*   merch     = (const int*)d_in[2];
    const float* card_emb  = (const float*)d_in[3];
    const float* merch_emb = (const float*)d_in[4];
    const float* pre_Wi = (const float*)d_in[5];
    const float* pre_bi = (const float*)d_in[6];
    const float* pre_Wh = (const float*)d_in[7];
    const float* pre_bh = (const float*)d_in[8];
    const float* pre_Wo = (const float*)d_in[9];
    const float* pre_bo = (const float*)d_in[10];
    const float* conv1_W = (const float*)d_in[11];
    const float* conv1_b = (const float*)d_in[12];
    const float* conv2_W = (const float*)d_in[13];
    const float* conv2_b = (const float*)d_in[14];
    const float* conv3_Wt = (const float*)d_in[15];
    const float* conv3_bt = (const float*)d_in[16];
    const float* conv3_Wo = (const float*)d_in[17];
    const float* conv3_bo = (const float*)d_in[18];
    const float* post_Wi = (const float*)d_in[19];
    const float* post_bi = (const float*)d_in[20];
    const float* post_Wh = (const float*)d_in[21];
    const float* post_bh = (const float*)d_in[22];
    const float* post_Wo = (const float*)d_in[23];
    const float* post_bo = (const float*)d_in[24];

    float* out = (float*)d_out;

    const int MTP = PAD128(NT);
    const int MCP = PAD128(NC);
    const int MMP = PAD128(NM);

    // ---- workspace carve ----
    char* ws = (char*)d_ws;
    size_t off = 0;
    auto alloc = [&](size_t bytes) -> char* {
        char* p = ws + off;
        off += (bytes + 255) & ~(size_t)255;
        return p;
    };
    int* cnt_c = (int*)alloc((size_t)NC * 4);
    int* cnt_m = (int*)alloc((size_t)NM * 4);
    int* cur_c = (int*)alloc((size_t)NC * 4);
    int* cur_m = (int*)alloc((size_t)NM * 4);
    size_t zero_bytes = (size_t)((char*)(cur_m + NM) - (char*)cnt_c);
    int* off_c = (int*)alloc((size_t)(NC + 1) * 4);
    int* off_m = (int*)alloc((size_t)(NM + 1) * 4);
    int* srt_c = (int*)alloc((size_t)NT * 4);
    int* srt_m = (int*)alloc((size_t)NT * 4);
    float* rs_c = (float*)alloc((size_t)NC * 4);
    float* rs_m = (float*)alloc((size_t)NM * 4);

    const int KP_WI = 416;
    _Float16* wi_h  = (_Float16*)alloc((size_t)HPRE * KP_WI * 2);
    _Float16* wi_l  = (_Float16*)alloc((size_t)HPRE * KP_WI * 2);
    _Float16* wh_h  = (_Float16*)alloc((size_t)HPRE * HPRE * 2);
    _Float16* wh_l  = (_Float16*)alloc((size_t)HPRE * HPRE * 2);
    _Float16* wo_h  = (_Float16*)alloc((size_t)DD * HPRE * 2);
    _Float16* wo_l  = (_Float16*)alloc((size_t)DD * HPRE * 2);
    _Float16* c1_h  = (_Float16*)alloc((size_t)4 * DD * DD * 2);
    _Float16* c1_l  = (_Float16*)alloc((size_t)4 * DD * DD * 2);
    _Float16* c2_h  = (_Float16*)alloc((size_t)4 * DD * DD * 2);
    _Float16* c2_l  = (_Float16*)alloc((size_t)4 * DD * DD * 2);
    _Float16* c3_h  = (_Float16*)alloc((size_t)2 * DOUT * DD * 2);
    _Float16* c3_l  = (_Float16*)alloc((size_t)2 * DOUT * DD * 2);
    _Float16* pi_h  = (_Float16*)alloc((size_t)HPOST * DOUT * 2);
    _Float16* pi_l  = (_Float16*)alloc((size_t)HPOST * DOUT * 2);
    _Float16* ph_h  = (_Float16*)alloc((size_t)HPOST * HPOST * 2);
    _Float16* ph_l  = (_Float16*)alloc((size_t)HPOST * HPOST * 2);

    // activation planes
    _Float16* ce_h   = (_Float16*)alloc((size_t)MCP * DD * 2);
    _Float16* ce_l   = (_Float16*)alloc((size_t)MCP * DD * 2);
    _Float16* me_h   = (_Float16*)alloc((size_t)MMP * DD * 2);
    _Float16* me_l   = (_Float16*)alloc((size_t)MMP * DD * 2);
    _Float16* bufA_h = (_Float16*)alloc((size_t)MTP * HPRE * 2);
    _Float16* bufA_l = (_Float16*)alloc((size_t)MTP * HPRE * 2);
    _Float16* bufB_h = (_Float16*)alloc((size_t)MTP * HPRE * 2);
    _Float16* bufB_l = (_Float16*)alloc((size_t)MTP * HPRE * 2);
    _Float16* agC_h  = (_Float16*)alloc((size_t)MCP * DD * 2);
    _Float16* agC_l  = (_Float16*)alloc((size_t)MCP * DD * 2);
    _Float16* agM_h  = (_Float16*)alloc((size_t)MMP * DD * 2);
    _Float16* agM_l  = (_Float16*)alloc((size_t)MMP * DD * 2);
    _Float16* h1c_h  = (_Float16*)alloc((size_t)MCP * DD * 2);
    _Float16* h1c_l  = (_Float16*)alloc((size_t)MCP * DD * 2);
    _Float16* h1m_h  = (_Float16*)alloc((size_t)MMP * DD * 2);
    _Float16* h1m_l  = (_Float16*)alloc((size_t)MMP * DD * 2);
    _Float16* h2c_h  = (_Float16*)alloc((size_t)MCP * DD * 2);
    _Float16* h2c_l  = (_Float16*)alloc((size_t)MCP * DD * 2);
    _Float16* h2m_h  = (_Float16*)alloc((size_t)MMP * DD * 2);
    _Float16* h2m_l  = (_Float16*)alloc((size_t)MMP * DD * 2);

    // fp32 buffers
    float* tf   = (float*)alloc((size_t)MTP * DD * 4);
    float* h1_t = (float*)alloc((size_t)MTP * DD * 4);
    float* h2_t = (float*)alloc((size_t)MTP * DD * 4);
    float* hc_p = (float*)alloc((size_t)MCP * DD * 4);
    float* hm_p = (float*)alloc((size_t)MMP * DD * 4);
    float* s2   = (float*)alloc((size_t)NT * 2 * 4);
    (void)ws_size; (void)in_sizes; (void)n_in; (void)out_size;

    // ---- degrees + CSR ----
    hipMemsetAsync(cnt_c, 0, zero_bytes, stream);
    count_kernel<<<(NT + 255) / 256, 256, 0, stream>>>(card, merch, cnt_c, cnt_m, NT);
    rsqrt_kernel<<<(NC + 255) / 256, 256, 0, stream>>>(cnt_c, rs_c, NC);
    rsqrt_kernel<<<(NM + 255) / 256, 256, 0, stream>>>(cnt_m, rs_m, NM);
    scan_excl<<<1, 1024, 0, stream>>>(cnt_c, off_c, NC);
    scan_excl<<<1, 1024, 0, stream>>>(cnt_m, off_m, NM);
    fill_sorted<<<(NT + 255) / 256, 256, 0, stream>>>(card, off_c, cur_c, srt_c, NT);
    fill_sorted<<<(NT + 255) / 256, 256, 0, stream>>>(merch, off_m, cur_m, srt_m, NT);

    // ---- split weights ----
    auto splitw = [&](const float* W, _Float16* h, _Float16* l, int K, int N, int Kpad, int nmat) {
        int total = nmat * N * Kpad;
        split_w<<<(total + 255) / 256, 256, 0, stream>>>(W, h, l, K, N, Kpad, nmat);
    };
    splitw(pre_Wi,   wi_h, wi_l, DIN,  HPRE,  KP_WI, 1);
    splitw(pre_Wh,   wh_h, wh_l, HPRE, HPRE,  HPRE,  1);
    splitw(pre_Wo,   wo_h, wo_l, HPRE, DD,    HPRE,  1);
    splitw(conv1_W,  c1_h, c1_l, DD,   DD,    DD,    4);
    splitw(conv2_W,  c2_h, c2_l, DD,   DD,    DD,    4);
    splitw(conv3_Wt, c3_h, c3_l, DD,   DOUT,  DD,    2);
    splitw(post_Wi,  pi_h, pi_l, DOUT, HPOST, DOUT,  1);
    splitw(post_Wh,  ph_h, ph_l, HPOST,HPOST, HPOST, 1);

    split_a<<<((MCP * (DD / 8)) + 255) / 256, 256, 0, stream>>>(card_emb, ce_h, ce_l, NC, MCP, DD);
    split_a<<<((MMP * (DD / 8)) + 255) / 256, 256, 0, stream>>>(merch_emb, me_h, me_l, NM, MMP, DD);

    const int WP  = DD * DD;
    const int WP3 = DOUT * DD;

    // ---- pre-FF: 390 -> 256 -> 256 -> 128 ----
    {
        const int nbm = (NT + 63) / 64;
        gemm_mfma<1, 2, 2, 2><<<dim3(nbm * 2), 256, 0, stream>>>(
            x_in, wi_h, wi_l, pre_bi, nullptr, nullptr, bufA_h, bufA_l,
            NT, DIN, HPRE, KP_WI, 1);
    }
    gemm_ps_launch(bufA_h, bufA_l, wh_h, wh_l, pre_bh, nullptr,
                   bufB_h, bufB_l, nullptr, NT, HPRE, HPRE, 1, stream);
    gemm_ps_launch(bufB_h, bufB_l, wo_h, wo_l, pre_bo, nullptr,
                   nullptr, nullptr, tf, NT, HPRE, DD, 0, stream);

    // ---- conv1 ----
    // card->target / merch->target: GEMM on small side, gather to targets
    gemm_ps_launch(ce_h, ce_l, c1_h + 0 * WP, c1_l + 0 * WP, nullptr, rs_c,
                   nullptr, nullptr, hc_p, NC, DD, DD, 0, stream);
    gemm_ps_launch(me_h, me_l, c1_h + 1 * WP, c1_l + 1 * WP, nullptr, rs_m,
                   nullptr, nullptr, hm_p, NM, DD, DD, 0, stream);
    gather2_kernel<<<(NT * (DD / 4) + 255) / 256, 256, 0, stream>>>(
        hc_p, hm_p, card, merch, conv1_b, conv1_b + DD, h1_t, NT, DD, 1);
    // target->card / target->merch: PRE-AGGREGATE then small GEMM
    agg_raw_kernel<<<(NC + 1) / 2, 256, 0, stream>>>(tf, off_c, srt_c, agC_h, agC_l, NC);
    agg_raw_kernel<<<(NM + 1) / 2, 256, 0, stream>>>(tf, off_m, srt_m, agM_h, agM_l, NM);
    gemm_ps_launch(agC_h, agC_l, c1_h + 2 * WP, c1_l + 2 * WP, conv1_b + 2 * DD, rs_c,
                   h1c_h, h1c_l, nullptr, NC, DD, DD, 1, stream);
    gemm_ps_launch(agM_h, agM_l, c1_h + 3 * WP, c1_l + 3 * WP, conv1_b + 3 * DD, rs_m,
                   h1m_h, h1m_l, nullptr, NM, DD, DD, 1, stream);

    // ---- conv2 ----
    gemm_ps_launch(h1c_h, h1c_l, c2_h + 0 * WP, c2_l + 0 * WP, nullptr, rs_c,
                   nullptr, nullptr, hc_p, NC, DD, DD, 0, stream);
    gemm_ps_launch(h1m_h, h1m_l, c2_h + 1 * WP, c2_l + 1 * WP, nullptr, rs_m,
                   nullptr, nullptr, hm_p, NM, DD, DD, 0, stream);
    gather2_kernel<<<(NT * (DD / 4) + 255) / 256, 256, 0, stream>>>(
        hc_p, hm_p, card, merch, conv2_b, conv2_b + DD, h2_t, NT, DD, 1);
    agg_raw_kernel<<<(NC + 1) / 2, 256, 0, stream>>>(h1_t, off_c, srt_c, agC_h, agC_l, NC);
    agg_raw_kernel<<<(NM + 1) / 2, 256, 0, stream>>>(h1_t, off_m, srt_m, agM_h, agM_l, NM);
    gemm_ps_launch(agC_h, agC_l, c2_h + 2 * WP, c2_l + 2 * WP, conv2_b + 2 * DD, rs_c,
                   h2c_h, h2c_l, nullptr, NC, DD, DD, 1, stream);
    gemm_ps_launch(agM_h, agM_l, c2_h + 3 * WP, c2_l + 3 * WP, conv2_b + 3 * DD, rs_m,
                   h2m_h, h2m_l, nullptr, NM, DD, DD, 1, stream);

    // ---- conv3 ----
    gemm_ps_launch(h2c_h, h2c_l, c3_h + 0 * WP3, c3_l + 0 * WP3, nullptr, rs_c,
                   nullptr, nullptr, hc_p, NC, DD, DOUT, 0, stream);
    gemm_ps_launch(h2m_h, h2m_l, c3_h + 1 * WP3, c3_l + 1 * WP3, nullptr, rs_m,
                   nullptr, nullptr, hm_p, NM, DD, DOUT, 0, stream);
    dot2_kernel<<<(NT + 3) / 4, 256, 0, stream>>>(h2_t, conv3_Wo, conv3_Wo + DD, s2, NT);
    agg_scalar_kernel<<<(NC + 255) / 256, 256, 0, stream>>>(s2, 0, off_c, srt_c, rs_c,
                                                            conv3_bo + 0, out + NT, NC);
    agg_scalar_kernel<<<(NM + 255) / 256, 256, 0, stream>>>(s2, 1, off_m, srt_m, rs_m,
                                                            conv3_bo + 1, out + NT + NC, NM);

    // ---- fused post-FF ----
    post_ff<<<dim3((NT + 127) / 128), 512, 0, stream>>>(
        hc_p, hm_p, card, merch, conv3_bt, conv3_bt + DOUT,
        pi_h, pi_l, post_bi, ph_h, ph_l, post_bh, post_Wo, post_bo, out, NT);
}